// Round 3
// baseline (589.674 us; speedup 1.0000x reference)
//
#include <hip/hip_runtime.h>
#include <hip/hip_bf16.h>
#include <math.h>
#include <stdint.h>

// Problem constants (from setup_inputs)
#define B_ 32
#define T_ 512
#define D_ 1024
#define N_ 50000
#define S_ 4096

// 1 / log(N+1) = 1 / log(50001)
#define INV_LOG_NP1 0.09242317f

typedef __attribute__((ext_vector_type(8))) short bf16x8;   // MFMA A/B frag (8 bf16)
typedef __attribute__((ext_vector_type(4))) float f32x4;    // MFMA C/D frag
typedef __attribute__((ext_vector_type(4))) short s16x4;    // 8B LDS/global store
typedef __attribute__((ext_vector_type(8))) short s16x8;    // 16B global store

// fp32 -> bf16 round-to-nearest-even
__device__ __forceinline__ short f2bf(float f) {
    unsigned u = __float_as_uint(f);
    u += 0x7fffu + ((u >> 16) & 1u);
    return (short)(u >> 16);
}

// log E[count] for log-uniform unique sampling (TF formula), fp32 like the ref
__device__ __forceinline__ float log_expected(int id) {
    float p  = log1pf(1.0f / ((float)id + 1.0f)) * INV_LOG_NP1;  // P(c)
    return logf(-expm1f((float)S_ * log1pf(-p)));                // log(1-(1-p)^S)
}

// async global->LDS, 16 B per lane; LDS dest = wave-uniform base + lane*16
__device__ __forceinline__ void gload_lds16(const short* g, short* l) {
    __builtin_amdgcn_global_load_lds(
        (const __attribute__((address_space(1))) void*)g,
        (__attribute__((address_space(3))) void*)l, 16, 0, 0);
}

// ---------------------------------------------------------------------------
// Kernel 0 (fast path): W fp32 -> bf16 table. Pure streaming convert.
__global__ __launch_bounds__(256) void convert_w_kernel(
    const float* __restrict__ W, short* __restrict__ Wbf)
{
    size_t i = ((size_t)blockIdx.x * 2048) + (size_t)threadIdx.x * 8;
    float4 a = *(const float4*)(W + i);
    float4 b = *(const float4*)(W + i + 4);
    s16x8 o = {f2bf(a.x), f2bf(a.y), f2bf(a.z), f2bf(a.w),
               f2bf(b.x), f2bf(b.y), f2bf(b.z), f2bf(b.w)};
    *(s16x8*)(Wbf + i) = o;
}

// ---------------------------------------------------------------------------
// Kernel 1: true logits. One wave per token. fp32 dot(x[b,t,:], W[label,:]).
// Fast variant also emits x in bf16 (fused convert: x is read here anyway).
template <bool EMIT_XBF>
__global__ __launch_bounds__(256) void true_logit_kernel(
    const float* __restrict__ x, const float* __restrict__ W,
    const float* __restrict__ bvec, const int* __restrict__ labels,
    float* __restrict__ true_logit, float* __restrict__ denom,
    short* __restrict__ xbf)
{
    int w = threadIdx.x >> 6, lane = threadIdx.x & 63;
    int token = blockIdx.x * 4 + w;             // grid = B*T/4, exact
    int lab = labels[token];
    const float4* xp = (const float4*)(x + (size_t)token * D_);
    const float4* wp = (const float4*)(W + (size_t)lab * D_);
    float acc = 0.0f;
#pragma unroll
    for (int j = 0; j < 4; ++j) {               // 1024 floats = 256 float4 / 64 lanes
        float4 a = xp[lane + 64 * j];
        float4 c = wp[lane + 64 * j];
        acc += a.x * c.x + a.y * c.y + a.z * c.z + a.w * c.w;
        if (EMIT_XBF) {
            s16x4 pa = {f2bf(a.x), f2bf(a.y), f2bf(a.z), f2bf(a.w)};
            *(s16x4*)(xbf + (size_t)token * D_ + (lane + 64 * j) * 4) = pa;
        }
    }
#pragma unroll
    for (int m = 32; m >= 1; m >>= 1) acc += __shfl_xor(acc, m);
    if (lane == 0) {
        float tl = acc + bvec[lab] - log_expected(lab);
        true_logit[token] = tl;
        denom[token] = __expf(tl);
    }
}

constexpr int BM = 128, BN = 128, BK = 32;

// ---------------------------------------------------------------------------
// Kernel 2 (FAST): fused sampled-logits GEMM + exp-sum epilogue, bf16 inputs,
// double-buffered global_load_lds(16B) staging.
//
// LDS tile layout: row = 64 B = 4 chunks of 16 B; chunk c of row r stored at
// slot (c ^ ((r>>1)&3)).  Fragment read (row lr, kblock lq) -> slot
// lq^((lr>>1)&3): consecutive 8 lanes cover all 32 banks (conflict-free).
// Staging lane rl*4+s loads global chunk s^((rl>>1)&3) (still 64B-coalesced
// within the row).
//
// Pipeline: stage(buf0) issued in prologue; each half-iter does
//   __syncthreads(); issue stage(next buf); ds_read+mfma(cur buf)
// so the barrier's vmcnt(0) drain waits on loads that had a full MFMA phase
// in flight.
__global__ __launch_bounds__(256) void sampled_gemm_bf16(
    const short* __restrict__ xbf, const short* __restrict__ Wbf,
    const float* __restrict__ bvec, const int* __restrict__ labels,
    const int* __restrict__ sampled, float* __restrict__ denom)
{
    __shared__ short At[2][BM * BK];     // 2 x 8 KB
    __shared__ short Bt[2][BN * BK];     // 2 x 8 KB
    __shared__ float colbias[BN];
    __shared__ int   ids[BN];
    __shared__ int   labT[BM];

    int bidx = blockIdx.x;            // grid = B * (T/BM) * (S/BN) = 32*4*32
    int b    = bidx >> 7;
    int rem  = bidx & 127;
    int mT   = rem >> 5;
    int nT   = rem & 31;

    int tid  = threadIdx.x;
    int w    = tid >> 6, lane = tid & 63;

    // ---- staging geometry ----
    int rl = lane >> 2;                      // 0..15 row within 16-row segment
    int sl = lane & 3;                       // LDS slot
    int c  = sl ^ ((rl >> 1) & 3);           // global chunk this lane loads
    int segA = 2 * w, segB = 2 * w + 1;      // wave w stages segments 2w,2w+1
    int tokBase = b * T_ + mT * BM;

    // B row ids for my two staged rows: direct global loads (L1-broadcast)
    int idr0 = sampled[b * S_ + nT * BN + segA * 16 + rl];
    int idr1 = sampled[b * S_ + nT * BN + segB * 16 + rl];

    const short* gA0 = xbf + (size_t)(tokBase + segA * 16 + rl) * D_ + c * 8;
    const short* gA1 = xbf + (size_t)(tokBase + segB * 16 + rl) * D_ + c * 8;
    const short* gB0 = Wbf + (size_t)idr0 * D_ + c * 8;
    const short* gB1 = Wbf + (size_t)idr1 * D_ + c * 8;
    short* lA0[2] = {&At[0][segA * 512], &At[1][segA * 512]};
    short* lA1[2] = {&At[0][segB * 512], &At[1][segB * 512]};
    short* lB0[2] = {&Bt[0][segA * 512], &Bt[1][segA * 512]};
    short* lB1[2] = {&Bt[0][segB * 512], &Bt[1][segB * 512]};

#define STAGE(buf, koff)                          \
    do {                                          \
        gload_lds16(gA0 + (koff), lA0[buf]);      \
        gload_lds16(gA1 + (koff), lA1[buf]);      \
        gload_lds16(gB0 + (koff), lB0[buf]);      \
        gload_lds16(gB1 + (koff), lB1[buf]);      \
    } while (0)

    // Issue first tile loads ASAP; prologue transcendentals overlap them.
    STAGE(0, 0);

    // ---- prologue: epilogue metadata into LDS ----
    if (tid < BN) {
        int id = sampled[b * S_ + nT * BN + tid];
        ids[tid] = id;
        colbias[tid] = bvec[id] - log_expected(id);
    } else {
        int i = tid - BN;
        labT[i] = labels[b * T_ + mT * BM + i];
    }

    f32x4 acc[4][4];
#pragma unroll
    for (int mi = 0; mi < 4; ++mi)
#pragma unroll
        for (int ni = 0; ni < 4; ++ni) acc[mi][ni] = (f32x4){0.f, 0.f, 0.f, 0.f};

    int waveM = w >> 1, waveN = w & 1;
    int lr = lane & 15, lq = lane >> 4;
    int sw = lq ^ ((lr >> 1) & 3);           // swizzled k-chunk slot for reads
    int aoff[4], boff[4];
#pragma unroll
    for (int i = 0; i < 4; ++i) {
        aoff[i] = (waveM * 64 + i * 16 + lr) * BK + sw * 8;
        boff[i] = (waveN * 64 + i * 16 + lr) * BK + sw * 8;
    }

#define COMPUTE(buf)                                                        \
    do {                                                                    \
        bf16x8 af[4], bfr[4];                                               \
        _Pragma("unroll")                                                   \
        for (int mi = 0; mi < 4; ++mi)                                      \
            af[mi] = *(const bf16x8*)&At[buf][aoff[mi]];                    \
        _Pragma("unroll")                                                   \
        for (int ni = 0; ni < 4; ++ni)                                      \
            bfr[ni] = *(const bf16x8*)&Bt[buf][boff[ni]];                   \
        _Pragma("unroll")                                                   \
        for (int mi = 0; mi < 4; ++mi)                                      \
            _Pragma("unroll")                                               \
            for (int ni = 0; ni < 4; ++ni)                                  \
                acc[mi][ni] = __builtin_amdgcn_mfma_f32_16x16x32_bf16(      \
                    af[mi], bfr[ni], acc[mi][ni], 0, 0, 0);                 \
    } while (0)

    for (int k0 = 0; k0 < D_; k0 += 2 * BK) {
        __syncthreads();                       // drains buf0 stage
        STAGE(1, k0 + BK);                     // prefetch next into buf1
        COMPUTE(0);
        __syncthreads();                       // drains buf1 stage
        if (k0 + 2 * BK < D_) STAGE(0, k0 + 2 * BK);
        COMPUTE(1);
    }
#undef STAGE
#undef COMPUTE

    // Epilogue: bias, accidental-hit mask, exp, row-sum, atomicAdd
    // C/D layout (verified m89/m91): col = lane&15, row = (lane>>4)*4 + reg
    float* dptr = denom + b * T_ + mT * BM;
#pragma unroll
    for (int mi = 0; mi < 4; ++mi) {
#pragma unroll
        for (int r = 0; r < 4; ++r) {
            int localRow = waveM * 64 + mi * 16 + lq * 4 + r;
            int lab = labT[localRow];
            float s = 0.0f;
#pragma unroll
            for (int ni = 0; ni < 4; ++ni) {
                int col = waveN * 64 + ni * 16 + lr;
                float v = acc[mi][ni][r] + colbias[col];
                s += (ids[col] == lab) ? 0.0f : __expf(v);
            }
            s += __shfl_xor(s, 1);
            s += __shfl_xor(s, 2);
            s += __shfl_xor(s, 4);
            s += __shfl_xor(s, 8);
            if (lr == 0) atomicAdd(&dptr[localRow], s);
        }
    }
}

// ---------------------------------------------------------------------------
// Kernel 2 (FALLBACK): register-staging fp32->bf16 GEMM (small-ws path).
__global__ __launch_bounds__(256) void sampled_gemm(
    const float* __restrict__ x, const float* __restrict__ W,
    const float* __restrict__ bvec, const int* __restrict__ labels,
    const int* __restrict__ sampled, float* __restrict__ denom)
{
    __shared__ short At[BM * BK];
    __shared__ short Bt[BN * BK];
    __shared__ float colbias[BN];
    __shared__ int   ids[BN];
    __shared__ int   labT[BM];

    int bidx = blockIdx.x;
    int b    = bidx >> 7;
    int rem  = bidx & 127;
    int mT   = rem >> 5;
    int nT   = rem & 31;
    int tid = threadIdx.x;

    if (tid < BN) {
        int id = sampled[b * S_ + nT * BN + tid];
        ids[tid] = id;
        colbias[tid] = bvec[id] - log_expected(id);
    } else {
        int i = tid - BN;
        labT[i] = labels[b * T_ + mT * BM + i];
    }
    __syncthreads();

    const float* asrc[4];
    const float* bsrc[4];
    int ch = tid & 7;
#pragma unroll
    for (int j = 0; j < 4; ++j) {
        int row = (tid >> 3) + 32 * j;
        asrc[j] = x + ((size_t)(b * T_ + mT * BM + row)) * D_ + ch * 4;
        bsrc[j] = W + (size_t)ids[row] * D_ + ch * 4;
    }

    f32x4 acc[4][4];
#pragma unroll
    for (int mi = 0; mi < 4; ++mi)
#pragma unroll
        for (int ni = 0; ni < 4; ++ni) acc[mi][ni] = (f32x4){0.f, 0.f, 0.f, 0.f};

    int w = tid >> 6, lane = tid & 63;
    int waveM = w >> 1, waveN = w & 1;
    int lr = lane & 15, lq = lane >> 4;

    for (int k0 = 0; k0 < D_; k0 += BK) {
        __syncthreads();
#pragma unroll
        for (int j = 0; j < 4; ++j) {
            int row = (tid >> 3) + 32 * j;
            float4 va = *(const float4*)(asrc[j] + k0);
            s16x4 pa = {f2bf(va.x), f2bf(va.y), f2bf(va.z), f2bf(va.w)};
            *(s16x4*)&At[row * BK + ch * 4] = pa;
            float4 vb = *(const float4*)(bsrc[j] + k0);
            s16x4 pb = {f2bf(vb.x), f2bf(vb.y), f2bf(vb.z), f2bf(vb.w)};
            *(s16x4*)&Bt[row * BK + ch * 4] = pb;
        }
        __syncthreads();
        bf16x8 af[4], bfr[4];
#pragma unroll
        for (int mi = 0; mi < 4; ++mi)
            af[mi] = *(const bf16x8*)&At[(waveM * 64 + mi * 16 + lr) * BK + lq * 8];
#pragma unroll
        for (int ni = 0; ni < 4; ++ni)
            bfr[ni] = *(const bf16x8*)&Bt[(waveN * 64 + ni * 16 + lr) * BK + lq * 8];
#pragma unroll
        for (int mi = 0; mi < 4; ++mi)
#pragma unroll
            for (int ni = 0; ni < 4; ++ni)
                acc[mi][ni] = __builtin_amdgcn_mfma_f32_16x16x32_bf16(
                    af[mi], bfr[ni], acc[mi][ni], 0, 0, 0);
    }

    float* dptr = denom + b * T_ + mT * BM;
#pragma unroll
    for (int mi = 0; mi < 4; ++mi) {
#pragma unroll
        for (int r = 0; r < 4; ++r) {
            int localRow = waveM * 64 + mi * 16 + lq * 4 + r;
            int lab = labT[localRow];
            float s = 0.0f;
#pragma unroll
            for (int ni = 0; ni < 4; ++ni) {
                int col = waveN * 64 + ni * 16 + lr;
                float v = acc[mi][ni][r] + colbias[col];
                s += (ids[col] == lab) ? 0.0f : __expf(v);
            }
            s += __shfl_xor(s, 1);
            s += __shfl_xor(s, 2);
            s += __shfl_xor(s, 4);
            s += __shfl_xor(s, 8);
            if (lr == 0) atomicAdd(&dptr[localRow], s);
        }
    }
}

// ---------------------------------------------------------------------------
// Kernel 3: token_loss = log(denom) - true_logit; out = 0.5 * mean
__global__ __launch_bounds__(256) void finalize_kernel(
    const float* __restrict__ true_logit, const float* __restrict__ denom,
    float* __restrict__ out)
{
    float s = 0.0f;
    for (int i = threadIdx.x; i < B_ * T_; i += 256)
        s += __logf(denom[i]) - true_logit[i];
#pragma unroll
    for (int m = 32; m >= 1; m >>= 1) s += __shfl_xor(s, m);
    __shared__ float wsum[4];
    if ((threadIdx.x & 63) == 0) wsum[threadIdx.x >> 6] = s;
    __syncthreads();
    if (threadIdx.x == 0)
        out[0] = 0.5f * (wsum[0] + wsum[1] + wsum[2] + wsum[3]) / (float)(B_ * T_);
}

// ---------------------------------------------------------------------------
extern "C" void kernel_launch(void* const* d_in, const int* in_sizes, int n_in,
                              void* d_out, int out_size, void* d_ws, size_t ws_size,
                              hipStream_t stream) {
    const float* x       = (const float*)d_in[0];   // [B,T,D]
    const float* W       = (const float*)d_in[1];   // [N,D]
    const float* bvec    = (const float*)d_in[2];   // [N]
    const int*   labels  = (const int*)d_in[3];     // [B,T]
    const int*   sampled = (const int*)d_in[4];     // [B,S]
    float* out = (float*)d_out;

    float* true_logit = (float*)d_ws;               // B*T floats
    float* denom      = true_logit + B_ * T_;       // B*T floats
    short* xbf        = (short*)(denom + B_ * T_);  // B*T*D bf16 (33.55 MB)
    short* Wbf        = xbf + (size_t)B_ * T_ * D_; // N*D bf16 (102.4 MB)

    const size_t NEED = (size_t)2 * B_ * T_ * 4
                      + (size_t)B_ * T_ * D_ * 2
                      + (size_t)N_ * D_ * 2;        // 136,085,504 B

    if (ws_size >= NEED) {
        convert_w_kernel<<<N_ * D_ / 2048, 256, 0, stream>>>(W, Wbf);
        true_logit_kernel<true><<<B_ * T_ / 4, 256, 0, stream>>>(
            x, W, bvec, labels, true_logit, denom, xbf);
        sampled_gemm_bf16<<<B_ * (T_ / BM) * (S_ / BN), 256, 0, stream>>>(
            xbf, Wbf, bvec, labels, sampled, denom);
    } else {
        true_logit_kernel<false><<<B_ * T_ / 4, 256, 0, stream>>>(
            x, W, bvec, labels, true_logit, denom, nullptr);
        sampled_gemm<<<B_ * (T_ / BM) * (S_ / BN), 256, 0, stream>>>(
            x, W, bvec, labels, sampled, denom);
    }
    finalize_kernel<<<1, 256, 0, stream>>>(true_logit, denom, out);
}

// Round 4
// 542.708 us; speedup vs baseline: 1.0865x; 1.0865x over previous
//
#include <hip/hip_runtime.h>
#include <hip/hip_bf16.h>
#include <math.h>
#include <stdint.h>

// Problem constants (from setup_inputs)
#define B_ 32
#define T_ 512
#define D_ 1024
#define N_ 50000
#define S_ 4096

// 1 / log(N+1) = 1 / log(50001)
#define INV_LOG_NP1 0.09242317f

typedef __attribute__((ext_vector_type(8))) short bf16x8;   // MFMA A/B frag (8 bf16)
typedef __attribute__((ext_vector_type(4))) float f32x4;    // MFMA C/D frag
typedef __attribute__((ext_vector_type(4))) short s16x4;    // 8B LDS/global store
typedef __attribute__((ext_vector_type(8))) short s16x8;    // 16B global store

// fp32 -> bf16 round-to-nearest-even
__device__ __forceinline__ short f2bf(float f) {
    unsigned u = __float_as_uint(f);
    u += 0x7fffu + ((u >> 16) & 1u);
    return (short)(u >> 16);
}

// log E[count] for log-uniform unique sampling (TF formula), fp32 like the ref
__device__ __forceinline__ float log_expected(int id) {
    float p  = log1pf(1.0f / ((float)id + 1.0f)) * INV_LOG_NP1;  // P(c)
    return logf(-expm1f((float)S_ * log1pf(-p)));                // log(1-(1-p)^S)
}

// async global->LDS, 16 B per lane; LDS dest = wave-uniform base + lane*16
__device__ __forceinline__ void gload_lds16(const short* g, short* l) {
    __builtin_amdgcn_global_load_lds(
        (const __attribute__((address_space(1))) void*)g,
        (__attribute__((address_space(3))) void*)l, 16, 0, 0);
}

// ---------------------------------------------------------------------------
// Kernel 0 (fast path): W fp32 -> bf16 table. Pure streaming convert.
__global__ __launch_bounds__(256) void convert_w_kernel(
    const float* __restrict__ W, short* __restrict__ Wbf)
{
    size_t i = ((size_t)blockIdx.x * 2048) + (size_t)threadIdx.x * 8;
    float4 a = *(const float4*)(W + i);
    float4 b = *(const float4*)(W + i + 4);
    s16x8 o = {f2bf(a.x), f2bf(a.y), f2bf(a.z), f2bf(a.w),
               f2bf(b.x), f2bf(b.y), f2bf(b.z), f2bf(b.w)};
    *(s16x8*)(Wbf + i) = o;
}

// ---------------------------------------------------------------------------
// Kernel 1: true logits. One wave per token. fp32 dot(x[b,t,:], W[label,:]).
// Fast variant also emits x in bf16 (fused convert: x is read here anyway).
template <bool EMIT_XBF>
__global__ __launch_bounds__(256) void true_logit_kernel(
    const float* __restrict__ x, const float* __restrict__ W,
    const float* __restrict__ bvec, const int* __restrict__ labels,
    float* __restrict__ true_logit, float* __restrict__ denom,
    short* __restrict__ xbf)
{
    int w = threadIdx.x >> 6, lane = threadIdx.x & 63;
    int token = blockIdx.x * 4 + w;             // grid = B*T/4, exact
    int lab = labels[token];
    const float4* xp = (const float4*)(x + (size_t)token * D_);
    const float4* wp = (const float4*)(W + (size_t)lab * D_);
    float acc = 0.0f;
#pragma unroll
    for (int j = 0; j < 4; ++j) {               // 1024 floats = 256 float4 / 64 lanes
        float4 a = xp[lane + 64 * j];
        float4 c = wp[lane + 64 * j];
        acc += a.x * c.x + a.y * c.y + a.z * c.z + a.w * c.w;
        if (EMIT_XBF) {
            s16x4 pa = {f2bf(a.x), f2bf(a.y), f2bf(a.z), f2bf(a.w)};
            *(s16x4*)(xbf + (size_t)token * D_ + (lane + 64 * j) * 4) = pa;
        }
    }
#pragma unroll
    for (int m = 32; m >= 1; m >>= 1) acc += __shfl_xor(acc, m);
    if (lane == 0) {
        float tl = acc + bvec[lab] - log_expected(lab);
        true_logit[token] = tl;
        denom[token] = __expf(tl);
    }
}

// ---------------------------------------------------------------------------
// Kernel 2 (FAST): fused sampled-logits GEMM + exp-sum epilogue, bf16 inputs,
// single-buffered (m97-style) global_load_lds(16B) staging, BK=64.
//
// LDS tile layout: row = BK bf16 = 128 B = 8 chunks of 16 B; chunk c of row r
// stored at slot (c ^ (r&7)).  b128 fragment reads: 8 consecutive lanes (rows
// r..r+7) hit 8 distinct slots -> all 32 banks, conflict-free.
// Staging: lane l loads global chunk (l&7)^(l>>3) of row (seg*8 + (l>>3));
// rows stay 128 B-coalesced.
//
// K-loop (m97 2-barrier shape; dbuf regressed in R3 — compiler inserts
// conservative vmcnt before other-buffer ds_reads):
//   [pre-issued STAGE k=0]
//   iter: { if(k0) { sync; STAGE; } sync /*drain*/; COMPUTE(2 ksteps); }
constexpr int BM = 128, BN = 128, BK = 64;

__global__ __launch_bounds__(256) void sampled_gemm_bf16(
    const short* __restrict__ xbf, const short* __restrict__ Wbf,
    const float* __restrict__ bvec, const int* __restrict__ labels,
    const int* __restrict__ sampled, float* __restrict__ denom)
{
    __shared__ short At[BM * BK];     // 16 KB
    __shared__ short Bt[BN * BK];     // 16 KB
    __shared__ float colbias[BN];
    __shared__ int   ids[BN];
    __shared__ int   labT[BM];

    int bidx = blockIdx.x;            // grid = B * (T/BM) * (S/BN) = 32*4*32
    int b    = bidx >> 7;
    int rem  = bidx & 127;
    int mT   = rem >> 5;
    int nT   = rem & 31;

    int tid  = threadIdx.x;
    int w    = tid >> 6, lane = tid & 63;

    // ---- staging geometry: 1 KB per issue = 8 rows x 128 B ----
    int r = lane >> 3;                       // 0..7 row within 8-row segment
    int s = lane & 7;                        // LDS slot (16 B units)
    int c = s ^ r;                           // global chunk this lane loads

    int tokBase = b * T_ + mT * BM;
    const short* gA[4];
    const short* gB[4];
    short* lA[4];
    short* lB[4];
#pragma unroll
    for (int j = 0; j < 4; ++j) {
        int seg = 4 * w + j;                 // wave w stages segments 4w..4w+3
        int row = seg * 8 + r;               // 0..127
        gA[j] = xbf + (size_t)(tokBase + row) * D_ + c * 8;
        int id = sampled[b * S_ + nT * BN + row];
        gB[j] = Wbf + (size_t)id * D_ + c * 8;
        lA[j] = At + seg * 512;              // 1024 B per segment (shorts)
        lB[j] = Bt + seg * 512;
    }

#define STAGE()                                                      \
    do {                                                             \
        _Pragma("unroll")                                            \
        for (int j = 0; j < 4; ++j) { gload_lds16(gA[j], lA[j]); gA[j] += BK; } \
        _Pragma("unroll")                                            \
        for (int j = 0; j < 4; ++j) { gload_lds16(gB[j], lB[j]); gB[j] += BK; } \
    } while (0)

    // Issue first tile ASAP; prologue transcendentals overlap the loads.
    STAGE();

    // ---- prologue: epilogue metadata into LDS ----
    if (tid < BN) {
        int id = sampled[b * S_ + nT * BN + tid];
        ids[tid] = id;
        colbias[tid] = bvec[id] - log_expected(id);
    } else {
        int i = tid - BN;
        labT[i] = labels[b * T_ + mT * BM + i];
    }

    f32x4 acc[4][4];
#pragma unroll
    for (int mi = 0; mi < 4; ++mi)
#pragma unroll
        for (int ni = 0; ni < 4; ++ni) acc[mi][ni] = (f32x4){0.f, 0.f, 0.f, 0.f};

    int waveM = w >> 1, waveN = w & 1;
    int lr = lane & 15, lq = lane >> 4;
    // Fragment row bases (shorts) and swizzled k-chunk offsets for 2 ksteps
    int aRow[4], bRow[4];
#pragma unroll
    for (int i = 0; i < 4; ++i) {
        aRow[i] = (waveM * 64 + i * 16 + lr) * BK;
        bRow[i] = (waveN * 64 + i * 16 + lr) * BK;
    }
    int slt[2];
    slt[0] = ((0 + lq) ^ (lr & 7)) * 8;
    slt[1] = ((4 + lq) ^ (lr & 7)) * 8;

    for (int k0 = 0; k0 < D_; k0 += BK) {
        if (k0) {
            __syncthreads();                  // LDS consumers of prev tile done
            STAGE();
        }
        __syncthreads();                      // drain staging (vmcnt(0))
#pragma unroll
        for (int t = 0; t < 2; ++t) {         // two K=32 steps per BK=64 tile
            bf16x8 af[4], bfr[4];
#pragma unroll
            for (int mi = 0; mi < 4; ++mi)
                af[mi] = *(const bf16x8*)&At[aRow[mi] + slt[t]];
#pragma unroll
            for (int ni = 0; ni < 4; ++ni)
                bfr[ni] = *(const bf16x8*)&Bt[bRow[ni] + slt[t]];
#pragma unroll
            for (int mi = 0; mi < 4; ++mi)
#pragma unroll
                for (int ni = 0; ni < 4; ++ni)
                    acc[mi][ni] = __builtin_amdgcn_mfma_f32_16x16x32_bf16(
                        af[mi], bfr[ni], acc[mi][ni], 0, 0, 0);
        }
    }
#undef STAGE

    // Epilogue: bias, accidental-hit mask, exp, row-sum, atomicAdd
    // C/D layout (verified m89/m91): col = lane&15, row = (lane>>4)*4 + reg
    float* dptr = denom + b * T_ + mT * BM;
#pragma unroll
    for (int mi = 0; mi < 4; ++mi) {
#pragma unroll
        for (int rr = 0; rr < 4; ++rr) {
            int localRow = waveM * 64 + mi * 16 + lq * 4 + rr;
            int lab = labT[localRow];
            float sum = 0.0f;
#pragma unroll
            for (int ni = 0; ni < 4; ++ni) {
                int col = waveN * 64 + ni * 16 + lr;
                float v = acc[mi][ni][rr] + colbias[col];
                sum += (ids[col] == lab) ? 0.0f : __expf(v);
            }
            sum += __shfl_xor(sum, 1);
            sum += __shfl_xor(sum, 2);
            sum += __shfl_xor(sum, 4);
            sum += __shfl_xor(sum, 8);
            if (lr == 0) atomicAdd(&dptr[localRow], sum);
        }
    }
}

// ---------------------------------------------------------------------------
// Kernel 2 (FALLBACK): register-staging fp32->bf16 GEMM (small-ws path).
__global__ __launch_bounds__(256) void sampled_gemm(
    const float* __restrict__ x, const float* __restrict__ W,
    const float* __restrict__ bvec, const int* __restrict__ labels,
    const int* __restrict__ sampled, float* __restrict__ denom)
{
    constexpr int FBK = 32;
    __shared__ short At[BM * FBK];
    __shared__ short Bt[BN * FBK];
    __shared__ float colbias[BN];
    __shared__ int   ids[BN];
    __shared__ int   labT[BM];

    int bidx = blockIdx.x;
    int b    = bidx >> 7;
    int rem  = bidx & 127;
    int mT   = rem >> 5;
    int nT   = rem & 31;
    int tid = threadIdx.x;

    if (tid < BN) {
        int id = sampled[b * S_ + nT * BN + tid];
        ids[tid] = id;
        colbias[tid] = bvec[id] - log_expected(id);
    } else {
        int i = tid - BN;
        labT[i] = labels[b * T_ + mT * BM + i];
    }
    __syncthreads();

    const float* asrc[4];
    const float* bsrc[4];
    int ch = tid & 7;
#pragma unroll
    for (int j = 0; j < 4; ++j) {
        int row = (tid >> 3) + 32 * j;
        asrc[j] = x + ((size_t)(b * T_ + mT * BM + row)) * D_ + ch * 4;
        bsrc[j] = W + (size_t)ids[row] * D_ + ch * 4;
    }

    f32x4 acc[4][4];
#pragma unroll
    for (int mi = 0; mi < 4; ++mi)
#pragma unroll
        for (int ni = 0; ni < 4; ++ni) acc[mi][ni] = (f32x4){0.f, 0.f, 0.f, 0.f};

    int w = tid >> 6, lane = tid & 63;
    int waveM = w >> 1, waveN = w & 1;
    int lr = lane & 15, lq = lane >> 4;

    for (int k0 = 0; k0 < D_; k0 += FBK) {
        __syncthreads();
#pragma unroll
        for (int j = 0; j < 4; ++j) {
            int row = (tid >> 3) + 32 * j;
            float4 va = *(const float4*)(asrc[j] + k0);
            s16x4 pa = {f2bf(va.x), f2bf(va.y), f2bf(va.z), f2bf(va.w)};
            *(s16x4*)&At[row * FBK + ch * 4] = pa;
            float4 vb = *(const float4*)(bsrc[j] + k0);
            s16x4 pb = {f2bf(vb.x), f2bf(vb.y), f2bf(vb.z), f2bf(vb.w)};
            *(s16x4*)&Bt[row * FBK + ch * 4] = pb;
        }
        __syncthreads();
        bf16x8 af[4], bfr[4];
#pragma unroll
        for (int mi = 0; mi < 4; ++mi)
            af[mi] = *(const bf16x8*)&At[(waveM * 64 + mi * 16 + lr) * FBK + lq * 8];
#pragma unroll
        for (int ni = 0; ni < 4; ++ni)
            bfr[ni] = *(const bf16x8*)&Bt[(waveN * 64 + ni * 16 + lr) * FBK + lq * 8];
#pragma unroll
        for (int mi = 0; mi < 4; ++mi)
#pragma unroll
            for (int ni = 0; ni < 4; ++ni)
                acc[mi][ni] = __builtin_amdgcn_mfma_f32_16x16x32_bf16(
                    af[mi], bfr[ni], acc[mi][ni], 0, 0, 0);
    }

    float* dptr = denom + b * T_ + mT * BM;
#pragma unroll
    for (int mi = 0; mi < 4; ++mi) {
#pragma unroll
        for (int rr = 0; rr < 4; ++rr) {
            int localRow = waveM * 64 + mi * 16 + lq * 4 + rr;
            int lab = labT[localRow];
            float sum = 0.0f;
#pragma unroll
            for (int ni = 0; ni < 4; ++ni) {
                int col = waveN * 64 + ni * 16 + lr;
                float v = acc[mi][ni][rr] + colbias[col];
                sum += (ids[col] == lab) ? 0.0f : __expf(v);
            }
            sum += __shfl_xor(sum, 1);
            sum += __shfl_xor(sum, 2);
            sum += __shfl_xor(sum, 4);
            sum += __shfl_xor(sum, 8);
            if (lr == 0) atomicAdd(&dptr[localRow], sum);
        }
    }
}

// ---------------------------------------------------------------------------
// Kernel 3: token_loss = log(denom) - true_logit; out = 0.5 * mean
__global__ __launch_bounds__(256) void finalize_kernel(
    const float* __restrict__ true_logit, const float* __restrict__ denom,
    float* __restrict__ out)
{
    float s = 0.0f;
    for (int i = threadIdx.x; i < B_ * T_; i += 256)
        s += __logf(denom[i]) - true_logit[i];
#pragma unroll
    for (int m = 32; m >= 1; m >>= 1) s += __shfl_xor(s, m);
    __shared__ float wsum[4];
    if ((threadIdx.x & 63) == 0) wsum[threadIdx.x >> 6] = s;
    __syncthreads();
    if (threadIdx.x == 0)
        out[0] = 0.5f * (wsum[0] + wsum[1] + wsum[2] + wsum[3]) / (float)(B_ * T_);
}

// ---------------------------------------------------------------------------
extern "C" void kernel_launch(void* const* d_in, const int* in_sizes, int n_in,
                              void* d_out, int out_size, void* d_ws, size_t ws_size,
                              hipStream_t stream) {
    const float* x       = (const float*)d_in[0];   // [B,T,D]
    const float* W       = (const float*)d_in[1];   // [N,D]
    const float* bvec    = (const float*)d_in[2];   // [N]
    const int*   labels  = (const int*)d_in[3];     // [B,T]
    const int*   sampled = (const int*)d_in[4];     // [B,S]
    float* out = (float*)d_out;

    float* true_logit = (float*)d_ws;               // B*T floats
    float* denom      = true_logit + B_ * T_;       // B*T floats
    short* xbf        = (short*)(denom + B_ * T_);  // B*T*D bf16 (33.55 MB)
    short* Wbf        = xbf + (size_t)B_ * T_ * D_; // N*D bf16 (102.4 MB)

    const size_t NEED = (size_t)2 * B_ * T_ * 4
                      + (size_t)B_ * T_ * D_ * 2
                      + (size_t)N_ * D_ * 2;        // 136,085,504 B

    if (ws_size >= NEED) {
        convert_w_kernel<<<N_ * D_ / 2048, 256, 0, stream>>>(W, Wbf);
        true_logit_kernel<true><<<B_ * T_ / 4, 256, 0, stream>>>(
            x, W, bvec, labels, true_logit, denom, xbf);
        sampled_gemm_bf16<<<B_ * (T_ / BM) * (S_ / BN), 256, 0, stream>>>(
            xbf, Wbf, bvec, labels, sampled, denom);
    } else {
        true_logit_kernel<false><<<B_ * T_ / 4, 256, 0, stream>>>(
            x, W, bvec, labels, true_logit, denom, nullptr);
        sampled_gemm<<<B_ * (T_ / BM) * (S_ / BN), 256, 0, stream>>>(
            x, W, bvec, labels, sampled, denom);
    }
    finalize_kernel<<<1, 256, 0, stream>>>(true_logit, denom, out);
}

// Round 5
// 484.455 us; speedup vs baseline: 1.2172x; 1.1202x over previous
//
#include <hip/hip_runtime.h>
#include <hip/hip_bf16.h>
#include <math.h>
#include <stdint.h>

// Problem constants (from setup_inputs)
#define B_ 32
#define T_ 512
#define D_ 1024
#define N_ 50000
#define S_ 4096

// 1 / log(N+1) = 1 / log(50001)
#define INV_LOG_NP1 0.09242317f

// W is pre-scaled by 64 when converting to fp8 e4m3 (raw W*0.02 lands in the
// subnormal zone); the GEMM accumulator is multiplied by 1/64 in the epilogue.
#define WSCALE 64.0f
#define INV_WSCALE 0.015625f

typedef __attribute__((ext_vector_type(8))) short bf16x8;   // bf16 MFMA A/B frag
typedef __attribute__((ext_vector_type(4))) float f32x4;    // MFMA C/D frag
typedef __attribute__((ext_vector_type(4))) short s16x4;    // 8B store
typedef long i64_t;                                         // fp8 MFMA A/B frag

// fp32 -> bf16 round-to-nearest-even (fallback path)
__device__ __forceinline__ short f2bf(float f) {
    unsigned u = __float_as_uint(f);
    u += 0x7fffu + ((u >> 16) & 1u);
    return (short)(u >> 16);
}

// pack 4 floats -> 4 fp8 e4m3 bytes (HW cvt, OCP format on gfx950)
__device__ __forceinline__ int pack_fp8x4(float a, float b, float c, float d) {
    int v = __builtin_amdgcn_cvt_pk_fp8_f32(a, b, 0, false);   // bytes 0,1
    v = __builtin_amdgcn_cvt_pk_fp8_f32(c, d, v, true);        // bytes 2,3
    return v;
}

// log E[count] for log-uniform unique sampling (TF formula), fp32 like the ref
__device__ __forceinline__ float log_expected(int id) {
    float p  = log1pf(1.0f / ((float)id + 1.0f)) * INV_LOG_NP1;  // P(c)
    return logf(-expm1f((float)S_ * log1pf(-p)));                // log(1-(1-p)^S)
}

// async global->LDS, 16 B per lane; LDS dest = wave-uniform base + lane*16
__device__ __forceinline__ void gload_lds16(const void* g, void* l) {
    __builtin_amdgcn_global_load_lds(
        (const __attribute__((address_space(1))) void*)g,
        (__attribute__((address_space(3))) void*)l, 16, 0, 0);
}

// ---------------------------------------------------------------------------
// Kernel 0 (fast path): W fp32 -> fp8 e4m3 table, scaled by WSCALE.
// grid 25000 x 256; each thread converts 8 elems (exactly covers N*D).
__global__ __launch_bounds__(256) void convert_w_kernel(
    const float* __restrict__ W, unsigned char* __restrict__ Wf8)
{
    size_t i = ((size_t)blockIdx.x * 2048) + (size_t)threadIdx.x * 8;
    float4 a = *(const float4*)(W + i);
    float4 b = *(const float4*)(W + i + 4);
    int2 o;
    o.x = pack_fp8x4(a.x * WSCALE, a.y * WSCALE, a.z * WSCALE, a.w * WSCALE);
    o.y = pack_fp8x4(b.x * WSCALE, b.y * WSCALE, b.z * WSCALE, b.w * WSCALE);
    *(int2*)(Wf8 + i) = o;
}

// ---------------------------------------------------------------------------
// Kernel 1: true logits. One wave per token. fp32 dot(x[b,t,:], W[label,:]).
// Fast variant also emits x in fp8 e4m3 (fused convert; x is read here anyway).
template <bool EMIT_XF8>
__global__ __launch_bounds__(256) void true_logit_kernel(
    const float* __restrict__ x, const float* __restrict__ W,
    const float* __restrict__ bvec, const int* __restrict__ labels,
    float* __restrict__ true_logit, float* __restrict__ denom,
    unsigned char* __restrict__ xf8)
{
    int w = threadIdx.x >> 6, lane = threadIdx.x & 63;
    int token = blockIdx.x * 4 + w;             // grid = B*T/4, exact
    int lab = labels[token];
    const float4* xp = (const float4*)(x + (size_t)token * D_);
    const float4* wp = (const float4*)(W + (size_t)lab * D_);
    float acc = 0.0f;
#pragma unroll
    for (int j = 0; j < 4; ++j) {               // 1024 floats = 256 float4 / 64 lanes
        float4 a = xp[lane + 64 * j];
        float4 c = wp[lane + 64 * j];
        acc += a.x * c.x + a.y * c.y + a.z * c.z + a.w * c.w;
        if (EMIT_XF8) {
            int o = pack_fp8x4(a.x, a.y, a.z, a.w);
            *(int*)(xf8 + (size_t)token * D_ + (lane + 64 * j) * 4) = o;
        }
    }
#pragma unroll
    for (int m = 32; m >= 1; m >>= 1) acc += __shfl_xor(acc, m);
    if (lane == 0) {
        float tl = acc + bvec[lab] - log_expected(lab);
        true_logit[token] = tl;
        denom[token] = __expf(tl);
    }
}

constexpr int BM = 128, BN = 128;

// ---------------------------------------------------------------------------
// Kernel 2 (FAST): fused sampled-logits GEMM + exp-sum epilogue, fp8 e4m3,
// single-buffered (m97-style) global_load_lds(16B) staging, BK=128 (bytes).
//
// LDS tile layout: row = 128 fp8 = 128 B = 8 chunks of 16 B; chunk c of row r
// stored at slot (c ^ (r&7)).  Staging: lane l loads chunk (l&7)^(l>>3) of
// row seg*8 + (l>>3); rows 128 B-coalesced in global.
// Fragment reads are ds_read_b64: kstep t wants row bytes [t*32+lq*8, +8) ->
// chunk 2t+(lq>>1), half lq&1; slot = chunk^(r&7). 16-lane phases land 2-way
// bank-aliased (free, m136).
//
// K-loop: 8 iters of { [sync; STAGE;] sync; 4 ksteps x 16 mfma }.
__global__ __launch_bounds__(256) void sampled_gemm_fp8(
    const unsigned char* __restrict__ xf8, const unsigned char* __restrict__ Wf8,
    const float* __restrict__ bvec, const int* __restrict__ labels,
    const int* __restrict__ sampled, float* __restrict__ denom)
{
    constexpr int BK = 128;           // K-bytes (= K elems, fp8)
    __shared__ unsigned char At[BM * BK];   // 16 KB
    __shared__ unsigned char Bt[BN * BK];   // 16 KB
    __shared__ float colbias[BN];
    __shared__ int   ids[BN];
    __shared__ int   labT[BM];

    int bidx = blockIdx.x;            // grid = B * (T/BM) * (S/BN) = 32*4*32
    int b    = bidx >> 7;
    int rem  = bidx & 127;
    int mT   = rem >> 5;
    int nT   = rem & 31;

    int tid  = threadIdx.x;
    int w    = tid >> 6, lane = tid & 63;

    // ---- staging geometry: 1 KB per issue = 8 rows x 128 B ----
    int r = lane >> 3;                       // 0..7 row within 8-row segment
    int s = lane & 7;                        // LDS slot (16 B units)
    int c = s ^ r;                           // global chunk this lane loads

    int tokBase = b * T_ + mT * BM;
    const unsigned char* gA[4];
    const unsigned char* gB[4];
    unsigned char* lA[4];
    unsigned char* lB[4];
#pragma unroll
    for (int j = 0; j < 4; ++j) {
        int seg = 4 * w + j;                 // wave w stages segments 4w..4w+3
        int row = seg * 8 + r;               // 0..127
        gA[j] = xf8 + (size_t)(tokBase + row) * D_ + c * 16;
        int id = sampled[b * S_ + nT * BN + row];
        gB[j] = Wf8 + (size_t)id * D_ + c * 16;
        lA[j] = At + seg * 1024;             // 1 KB per segment
        lB[j] = Bt + seg * 1024;
    }

#define STAGE()                                                      \
    do {                                                             \
        _Pragma("unroll")                                            \
        for (int j = 0; j < 4; ++j) { gload_lds16(gA[j], lA[j]); gA[j] += BK; } \
        _Pragma("unroll")                                            \
        for (int j = 0; j < 4; ++j) { gload_lds16(gB[j], lB[j]); gB[j] += BK; } \
    } while (0)

    // Issue first tile ASAP; prologue transcendentals overlap the loads.
    STAGE();

    // ---- prologue: epilogue metadata into LDS ----
    if (tid < BN) {
        int id = sampled[b * S_ + nT * BN + tid];
        ids[tid] = id;
        colbias[tid] = bvec[id] - log_expected(id);
    } else {
        int i = tid - BN;
        labT[i] = labels[b * T_ + mT * BM + i];
    }

    f32x4 acc[4][4];
#pragma unroll
    for (int mi = 0; mi < 4; ++mi)
#pragma unroll
        for (int ni = 0; ni < 4; ++ni) acc[mi][ni] = (f32x4){0.f, 0.f, 0.f, 0.f};

    int waveM = w >> 1, waveN = w & 1;
    int lr = lane & 15, lq = lane >> 4;
    // Fragment row byte-bases and per-kstep swizzled byte offsets
    int aRow[4], bRow[4];
#pragma unroll
    for (int i = 0; i < 4; ++i) {
        aRow[i] = (waveM * 64 + i * 16 + lr) * BK;
        bRow[i] = (waveN * 64 + i * 16 + lr) * BK;
    }
    int offT[4];
#pragma unroll
    for (int t = 0; t < 4; ++t) {
        int chunk = 2 * t + (lq >> 1);
        offT[t] = ((chunk ^ (lr & 7)) * 16) + (lq & 1) * 8;
    }

    for (int k0 = 0; k0 < D_; k0 += BK) {
        if (k0) {
            __syncthreads();                  // LDS consumers of prev tile done
            STAGE();
        }
        __syncthreads();                      // drain staging (vmcnt(0))
#pragma unroll
        for (int t = 0; t < 4; ++t) {         // four K=32 steps per BK=128 tile
            i64_t af[4], bfr[4];
#pragma unroll
            for (int mi = 0; mi < 4; ++mi)
                af[mi] = *(const i64_t*)(At + aRow[mi] + offT[t]);
#pragma unroll
            for (int ni = 0; ni < 4; ++ni)
                bfr[ni] = *(const i64_t*)(Bt + bRow[ni] + offT[t]);
#pragma unroll
            for (int mi = 0; mi < 4; ++mi)
#pragma unroll
                for (int ni = 0; ni < 4; ++ni)
                    acc[mi][ni] = __builtin_amdgcn_mfma_f32_16x16x32_fp8_fp8(
                        af[mi], bfr[ni], acc[mi][ni], 0, 0, 0);
        }
    }
#undef STAGE

    // Epilogue: 1/WSCALE, bias, accidental-hit mask, exp, row-sum, atomicAdd
    // C/D layout (verified m89/m91): col = lane&15, row = (lane>>4)*4 + reg
    float* dptr = denom + b * T_ + mT * BM;
#pragma unroll
    for (int mi = 0; mi < 4; ++mi) {
#pragma unroll
        for (int rr = 0; rr < 4; ++rr) {
            int localRow = waveM * 64 + mi * 16 + lq * 4 + rr;
            int lab = labT[localRow];
            float sum = 0.0f;
#pragma unroll
            for (int ni = 0; ni < 4; ++ni) {
                int col = waveN * 64 + ni * 16 + lr;
                float v = acc[mi][ni][rr] * INV_WSCALE + colbias[col];
                sum += (ids[col] == lab) ? 0.0f : __expf(v);
            }
            sum += __shfl_xor(sum, 1);
            sum += __shfl_xor(sum, 2);
            sum += __shfl_xor(sum, 4);
            sum += __shfl_xor(sum, 8);
            if (lr == 0) atomicAdd(&dptr[localRow], sum);
        }
    }
}

// ---------------------------------------------------------------------------
// Kernel 2 (FALLBACK): register-staging fp32->bf16 GEMM (small-ws path).
__global__ __launch_bounds__(256) void sampled_gemm(
    const float* __restrict__ x, const float* __restrict__ W,
    const float* __restrict__ bvec, const int* __restrict__ labels,
    const int* __restrict__ sampled, float* __restrict__ denom)
{
    constexpr int FBK = 32;
    __shared__ short At[BM * FBK];
    __shared__ short Bt[BN * FBK];
    __shared__ float colbias[BN];
    __shared__ int   ids[BN];
    __shared__ int   labT[BM];

    int bidx = blockIdx.x;
    int b    = bidx >> 7;
    int rem  = bidx & 127;
    int mT   = rem >> 5;
    int nT   = rem & 31;
    int tid = threadIdx.x;

    if (tid < BN) {
        int id = sampled[b * S_ + nT * BN + tid];
        ids[tid] = id;
        colbias[tid] = bvec[id] - log_expected(id);
    } else {
        int i = tid - BN;
        labT[i] = labels[b * T_ + mT * BM + i];
    }
    __syncthreads();

    const float* asrc[4];
    const float* bsrc[4];
    int ch = tid & 7;
#pragma unroll
    for (int j = 0; j < 4; ++j) {
        int row = (tid >> 3) + 32 * j;
        asrc[j] = x + ((size_t)(b * T_ + mT * BM + row)) * D_ + ch * 4;
        bsrc[j] = W + (size_t)ids[row] * D_ + ch * 4;
    }

    f32x4 acc[4][4];
#pragma unroll
    for (int mi = 0; mi < 4; ++mi)
#pragma unroll
        for (int ni = 0; ni < 4; ++ni) acc[mi][ni] = (f32x4){0.f, 0.f, 0.f, 0.f};

    int w = tid >> 6, lane = tid & 63;
    int waveM = w >> 1, waveN = w & 1;
    int lr = lane & 15, lq = lane >> 4;

    for (int k0 = 0; k0 < D_; k0 += FBK) {
        __syncthreads();
#pragma unroll
        for (int j = 0; j < 4; ++j) {
            int row = (tid >> 3) + 32 * j;
            float4 va = *(const float4*)(asrc[j] + k0);
            s16x4 pa = {f2bf(va.x), f2bf(va.y), f2bf(va.z), f2bf(va.w)};
            *(s16x4*)&At[row * FBK + ch * 4] = pa;
            float4 vb = *(const float4*)(bsrc[j] + k0);
            s16x4 pb = {f2bf(vb.x), f2bf(vb.y), f2bf(vb.z), f2bf(vb.w)};
            *(s16x4*)&Bt[row * FBK + ch * 4] = pb;
        }
        __syncthreads();
        bf16x8 af[4], bfr[4];
#pragma unroll
        for (int mi = 0; mi < 4; ++mi)
            af[mi] = *(const bf16x8*)&At[(waveM * 64 + mi * 16 + lr) * FBK + lq * 8];
#pragma unroll
        for (int ni = 0; ni < 4; ++ni)
            bfr[ni] = *(const bf16x8*)&Bt[(waveN * 64 + ni * 16 + lr) * FBK + lq * 8];
#pragma unroll
        for (int mi = 0; mi < 4; ++mi)
#pragma unroll
            for (int ni = 0; ni < 4; ++ni)
                acc[mi][ni] = __builtin_amdgcn_mfma_f32_16x16x32_bf16(
                    af[mi], bfr[ni], acc[mi][ni], 0, 0, 0);
    }

    float* dptr = denom + b * T_ + mT * BM;
#pragma unroll
    for (int mi = 0; mi < 4; ++mi) {
#pragma unroll
        for (int rr = 0; rr < 4; ++rr) {
            int localRow = waveM * 64 + mi * 16 + lq * 4 + rr;
            int lab = labT[localRow];
            float sum = 0.0f;
#pragma unroll
            for (int ni = 0; ni < 4; ++ni) {
                int col = waveN * 64 + ni * 16 + lr;
                float v = acc[mi][ni][rr] + colbias[col];
                sum += (ids[col] == lab) ? 0.0f : __expf(v);
            }
            sum += __shfl_xor(sum, 1);
            sum += __shfl_xor(sum, 2);
            sum += __shfl_xor(sum, 4);
            sum += __shfl_xor(sum, 8);
            if (lr == 0) atomicAdd(&dptr[localRow], sum);
        }
    }
}

// ---------------------------------------------------------------------------
// Kernel 3: token_loss = log(denom) - true_logit; out = 0.5 * mean
__global__ __launch_bounds__(256) void finalize_kernel(
    const float* __restrict__ true_logit, const float* __restrict__ denom,
    float* __restrict__ out)
{
    float s = 0.0f;
    for (int i = threadIdx.x; i < B_ * T_; i += 256)
        s += __logf(denom[i]) - true_logit[i];
#pragma unroll
    for (int m = 32; m >= 1; m >>= 1) s += __shfl_xor(s, m);
    __shared__ float wsum[4];
    if ((threadIdx.x & 63) == 0) wsum[threadIdx.x >> 6] = s;
    __syncthreads();
    if (threadIdx.x == 0)
        out[0] = 0.5f * (wsum[0] + wsum[1] + wsum[2] + wsum[3]) / (float)(B_ * T_);
}

// ---------------------------------------------------------------------------
extern "C" void kernel_launch(void* const* d_in, const int* in_sizes, int n_in,
                              void* d_out, int out_size, void* d_ws, size_t ws_size,
                              hipStream_t stream) {
    const float* x       = (const float*)d_in[0];   // [B,T,D]
    const float* W       = (const float*)d_in[1];   // [N,D]
    const float* bvec    = (const float*)d_in[2];   // [N]
    const int*   labels  = (const int*)d_in[3];     // [B,T]
    const int*   sampled = (const int*)d_in[4];     // [B,S]
    float* out = (float*)d_out;

    float* true_logit   = (float*)d_ws;                 // B*T floats
    float* denom        = true_logit + B_ * T_;         // B*T floats
    unsigned char* xf8  = (unsigned char*)(denom + B_ * T_);  // B*T*D fp8 (16.8 MB)
    unsigned char* Wf8  = xf8 + (size_t)B_ * T_ * D_;   // N*D fp8 (51.2 MB)

    const size_t NEED = (size_t)2 * B_ * T_ * 4
                      + (size_t)B_ * T_ * D_
                      + (size_t)N_ * D_;               // ~68.2 MB

    if (ws_size >= NEED) {
        convert_w_kernel<<<N_ * D_ / 2048, 256, 0, stream>>>(W, Wf8);
        true_logit_kernel<true><<<B_ * T_ / 4, 256, 0, stream>>>(
            x, W, bvec, labels, true_logit, denom, xf8);
        sampled_gemm_fp8<<<B_ * (T_ / BM) * (S_ / BN), 256, 0, stream>>>(
            xf8, Wf8, bvec, labels, sampled, denom);
    } else {
        true_logit_kernel<false><<<B_ * T_ / 4, 256, 0, stream>>>(
            x, W, bvec, labels, true_logit, denom, nullptr);
        sampled_gemm<<<B_ * (T_ / BM) * (S_ / BN), 256, 0, stream>>>(
            x, W, bvec, labels, sampled, denom);
    }
    finalize_kernel<<<1, 256, 0, stream>>>(true_logit, denom, out);
}

// Round 6
// 482.935 us; speedup vs baseline: 1.2210x; 1.0031x over previous
//
#include <hip/hip_runtime.h>
#include <hip/hip_bf16.h>
#include <math.h>
#include <stdint.h>

// Problem constants (from setup_inputs)
#define B_ 32
#define T_ 512
#define D_ 1024
#define N_ 50000
#define S_ 4096

// 1 / log(N+1) = 1 / log(50001)
#define INV_LOG_NP1 0.09242317f

// W is pre-scaled by 64 when converting to fp8 e4m3 (raw W*0.02 lands in the
// subnormal zone); the GEMM accumulator is multiplied by 1/64 in the epilogue.
#define WSCALE 64.0f
#define INV_WSCALE 0.015625f
#define LOG2E 1.4426950408889634f

typedef __attribute__((ext_vector_type(8))) short bf16x8;   // bf16 MFMA A/B frag
typedef __attribute__((ext_vector_type(4))) float f32x4;    // MFMA C/D frag
typedef __attribute__((ext_vector_type(4))) short s16x4;    // 8B store
typedef long i64_t;                                         // fp8 MFMA A/B frag

// fp32 -> bf16 round-to-nearest-even (fallback path)
__device__ __forceinline__ short f2bf(float f) {
    unsigned u = __float_as_uint(f);
    u += 0x7fffu + ((u >> 16) & 1u);
    return (short)(u >> 16);
}

// pack 4 floats -> 4 fp8 e4m3 bytes (HW cvt, OCP format on gfx950)
__device__ __forceinline__ int pack_fp8x4(float a, float b, float c, float d) {
    int v = __builtin_amdgcn_cvt_pk_fp8_f32(a, b, 0, false);   // bytes 0,1
    v = __builtin_amdgcn_cvt_pk_fp8_f32(c, d, v, true);        // bytes 2,3
    return v;
}

// log E[count] for log-uniform unique sampling (TF formula), fp32 like the ref
__device__ __forceinline__ float log_expected(int id) {
    float p  = log1pf(1.0f / ((float)id + 1.0f)) * INV_LOG_NP1;  // P(c)
    return logf(-expm1f((float)S_ * log1pf(-p)));                // log(1-(1-p)^S)
}

// async global->LDS, 16 B per lane; LDS dest = wave-uniform base + lane*16
__device__ __forceinline__ void gload_lds16(const void* g, void* l) {
    __builtin_amdgcn_global_load_lds(
        (const __attribute__((address_space(1))) void*)g,
        (__attribute__((address_space(3))) void*)l, 16, 0, 0);
}

// ---------------------------------------------------------------------------
// Kernel 0 (fast path): W fp32 -> fp8 e4m3 table, scaled by WSCALE.
// grid 25000 x 256; each thread converts 8 elems (exactly covers N*D).
__global__ __launch_bounds__(256) void convert_w_kernel(
    const float* __restrict__ W, unsigned char* __restrict__ Wf8)
{
    size_t i = ((size_t)blockIdx.x * 2048) + (size_t)threadIdx.x * 8;
    float4 a = *(const float4*)(W + i);
    float4 b = *(const float4*)(W + i + 4);
    int2 o;
    o.x = pack_fp8x4(a.x * WSCALE, a.y * WSCALE, a.z * WSCALE, a.w * WSCALE);
    o.y = pack_fp8x4(b.x * WSCALE, b.y * WSCALE, b.z * WSCALE, b.w * WSCALE);
    *(int2*)(Wf8 + i) = o;
}

// ---------------------------------------------------------------------------
// Kernel 1: true logits. One wave per token. fp32 dot(x[b,t,:], W[label,:]).
// Fast variant also emits x in fp8 e4m3 (fused convert; x is read here anyway).
template <bool EMIT_XF8>
__global__ __launch_bounds__(256) void true_logit_kernel(
    const float* __restrict__ x, const float* __restrict__ W,
    const float* __restrict__ bvec, const int* __restrict__ labels,
    float* __restrict__ true_logit, float* __restrict__ denom,
    unsigned char* __restrict__ xf8)
{
    int w = threadIdx.x >> 6, lane = threadIdx.x & 63;
    int token = blockIdx.x * 4 + w;             // grid = B*T/4, exact
    int lab = labels[token];
    const float4* xp = (const float4*)(x + (size_t)token * D_);
    const float4* wp = (const float4*)(W + (size_t)lab * D_);
    float acc = 0.0f;
#pragma unroll
    for (int j = 0; j < 4; ++j) {               // 1024 floats = 256 float4 / 64 lanes
        float4 a = xp[lane + 64 * j];
        float4 c = wp[lane + 64 * j];
        acc += a.x * c.x + a.y * c.y + a.z * c.z + a.w * c.w;
        if (EMIT_XF8) {
            int o = pack_fp8x4(a.x, a.y, a.z, a.w);
            *(int*)(xf8 + (size_t)token * D_ + (lane + 64 * j) * 4) = o;
        }
    }
#pragma unroll
    for (int m = 32; m >= 1; m >>= 1) acc += __shfl_xor(acc, m);
    if (lane == 0) {
        float tl = acc + bvec[lab] - log_expected(lab);
        true_logit[token] = tl;
        denom[token] = __expf(tl);
    }
}

constexpr int BM = 128, BN = 128;

// ---------------------------------------------------------------------------
// Kernel 2 (FAST): fused sampled-logits GEMM + exp-sum epilogue, fp8 e4m3,
// single-buffered (m97-style) global_load_lds(16B) staging, BK=128 (bytes).
//
// K-PERMUTATION TRICK: the GEMM result is invariant under any permutation of
// the K index applied to both A and B.  We relabel so that MFMA kstep t, lane
// quad lq (=lane>>4) consumes global k = lq*32 + t*8..+7.  Then a lane's data
// for a kstep-PAIR tp (t=2tp,2tp+1) is 16 contiguous global bytes = exactly
// one staged 16-B chunk (index 2lq+tp) -> conflict-free ds_read_b128:
// 8-lane phases read slots (2lq+tp)^(lr&7) = 8 distinct slots x 4 banks = all
// 32 banks.  Halves ds_read instruction count vs b64-per-kstep.
//
// LDS layout (unchanged): row = 128 B = 8 chunks of 16 B; chunk c of row r at
// slot c^(r&7).  Staging: lane l loads chunk (l&7)^(l>>3) of row seg*8+(l>>3).
//
// K-loop: 8 iters of { [sync; STAGE;] sync; 2 pair-steps x (2x16) mfma }.
__global__ __launch_bounds__(256) void sampled_gemm_fp8(
    const unsigned char* __restrict__ xf8, const unsigned char* __restrict__ Wf8,
    const float* __restrict__ bvec, const int* __restrict__ labels,
    const int* __restrict__ sampled, float* __restrict__ denom)
{
    constexpr int BK = 128;           // K-bytes (= K elems, fp8)
    __shared__ unsigned char At[BM * BK];   // 16 KB
    __shared__ unsigned char Bt[BN * BK];   // 16 KB
    __shared__ float colbias[BN];     // (b - logE) * log2(e)
    __shared__ int   ids[BN];
    __shared__ int   labT[BM];

    int bidx = blockIdx.x;            // grid = B * (T/BM) * (S/BN) = 32*4*32
    int b    = bidx >> 7;
    int rem  = bidx & 127;
    int mT   = rem >> 5;
    int nT   = rem & 31;

    int tid  = threadIdx.x;
    int w    = tid >> 6, lane = tid & 63;

    // ---- staging geometry: 1 KB per issue = 8 rows x 128 B ----
    int r = lane >> 3;                       // 0..7 row within 8-row segment
    int s = lane & 7;                        // LDS slot (16 B units)
    int c = s ^ r;                           // global chunk this lane loads

    int tokBase = b * T_ + mT * BM;
    const unsigned char* gA[4];
    const unsigned char* gB[4];
    unsigned char* lA[4];
    unsigned char* lB[4];
#pragma unroll
    for (int j = 0; j < 4; ++j) {
        int seg = 4 * w + j;                 // wave w stages segments 4w..4w+3
        int row = seg * 8 + r;               // 0..127
        gA[j] = xf8 + (size_t)(tokBase + row) * D_ + c * 16;
        int id = sampled[b * S_ + nT * BN + row];
        gB[j] = Wf8 + (size_t)id * D_ + c * 16;
        lA[j] = At + seg * 1024;             // 1 KB per segment
        lB[j] = Bt + seg * 1024;
    }

#define STAGE()                                                      \
    do {                                                             \
        _Pragma("unroll")                                            \
        for (int j = 0; j < 4; ++j) { gload_lds16(gA[j], lA[j]); gA[j] += BK; } \
        _Pragma("unroll")                                            \
        for (int j = 0; j < 4; ++j) { gload_lds16(gB[j], lB[j]); gB[j] += BK; } \
    } while (0)

    // Issue first tile ASAP; prologue transcendentals overlap the loads.
    STAGE();

    // ---- prologue: epilogue metadata into LDS ----
    if (tid < BN) {
        int id = sampled[b * S_ + nT * BN + tid];
        ids[tid] = id;
        colbias[tid] = (bvec[id] - log_expected(id)) * LOG2E;
    } else {
        int i = tid - BN;
        labT[i] = labels[b * T_ + mT * BM + i];
    }

    f32x4 acc[4][4];
#pragma unroll
    for (int mi = 0; mi < 4; ++mi)
#pragma unroll
        for (int ni = 0; ni < 4; ++ni) acc[mi][ni] = (f32x4){0.f, 0.f, 0.f, 0.f};

    int waveM = w >> 1, waveN = w & 1;
    int lr = lane & 15, lq = lane >> 4;
    // Fragment row byte-bases and per-pair swizzled chunk offsets
    int aRow[4], bRow[4];
#pragma unroll
    for (int i = 0; i < 4; ++i) {
        aRow[i] = (waveM * 64 + i * 16 + lr) * BK;
        bRow[i] = (waveN * 64 + i * 16 + lr) * BK;
    }
    int offP[2];
#pragma unroll
    for (int tp = 0; tp < 2; ++tp)
        offP[tp] = ((2 * lq + tp) ^ (lr & 7)) * 16;

    for (int k0 = 0; k0 < D_; k0 += BK) {
        if (k0) {
            __syncthreads();                  // LDS consumers of prev tile done
            STAGE();
        }
        __syncthreads();                      // drain staging (vmcnt(0))
#pragma unroll
        for (int tp = 0; tp < 2; ++tp) {      // two kstep-pairs per BK=128 tile
            long2 av[4], bv[4];
#pragma unroll
            for (int mi = 0; mi < 4; ++mi)
                av[mi] = *(const long2*)(At + aRow[mi] + offP[tp]);
#pragma unroll
            for (int ni = 0; ni < 4; ++ni)
                bv[ni] = *(const long2*)(Bt + bRow[ni] + offP[tp]);
#pragma unroll
            for (int mi = 0; mi < 4; ++mi)
#pragma unroll
                for (int ni = 0; ni < 4; ++ni)
                    acc[mi][ni] = __builtin_amdgcn_mfma_f32_16x16x32_fp8_fp8(
                        av[mi].x, bv[ni].x, acc[mi][ni], 0, 0, 0);
#pragma unroll
            for (int mi = 0; mi < 4; ++mi)
#pragma unroll
                for (int ni = 0; ni < 4; ++ni)
                    acc[mi][ni] = __builtin_amdgcn_mfma_f32_16x16x32_fp8_fp8(
                        av[mi].y, bv[ni].y, acc[mi][ni], 0, 0, 0);
        }
    }
#undef STAGE

    // Epilogue: exp2-domain (acc and bias pre-scaled by log2e), accidental-hit
    // mask, row-sum, atomicAdd.
    // C/D layout (verified m89/m91): col = lane&15, row = (lane>>4)*4 + reg
    const float accScale = INV_WSCALE * LOG2E;
    float* dptr = denom + b * T_ + mT * BM;
#pragma unroll
    for (int mi = 0; mi < 4; ++mi) {
#pragma unroll
        for (int rr = 0; rr < 4; ++rr) {
            int localRow = waveM * 64 + mi * 16 + lq * 4 + rr;
            int lab = labT[localRow];
            float sum = 0.0f;
#pragma unroll
            for (int ni = 0; ni < 4; ++ni) {
                int col = waveN * 64 + ni * 16 + lr;
                float v = acc[mi][ni][rr] * accScale + colbias[col];
                sum += (ids[col] == lab) ? 0.0f : exp2f(v);
            }
            sum += __shfl_xor(sum, 1);
            sum += __shfl_xor(sum, 2);
            sum += __shfl_xor(sum, 4);
            sum += __shfl_xor(sum, 8);
            if (lr == 0) atomicAdd(&dptr[localRow], sum);
        }
    }
}

// ---------------------------------------------------------------------------
// Kernel 2 (FALLBACK): register-staging fp32->bf16 GEMM (small-ws path).
__global__ __launch_bounds__(256) void sampled_gemm(
    const float* __restrict__ x, const float* __restrict__ W,
    const float* __restrict__ bvec, const int* __restrict__ labels,
    const int* __restrict__ sampled, float* __restrict__ denom)
{
    constexpr int FBK = 32;
    __shared__ short At[BM * FBK];
    __shared__ short Bt[BN * FBK];
    __shared__ float colbias[BN];
    __shared__ int   ids[BN];
    __shared__ int   labT[BM];

    int bidx = blockIdx.x;
    int b    = bidx >> 7;
    int rem  = bidx & 127;
    int mT   = rem >> 5;
    int nT   = rem & 31;
    int tid = threadIdx.x;

    if (tid < BN) {
        int id = sampled[b * S_ + nT * BN + tid];
        ids[tid] = id;
        colbias[tid] = bvec[id] - log_expected(id);
    } else {
        int i = tid - BN;
        labT[i] = labels[b * T_ + mT * BM + i];
    }
    __syncthreads();

    const float* asrc[4];
    const float* bsrc[4];
    int ch = tid & 7;
#pragma unroll
    for (int j = 0; j < 4; ++j) {
        int row = (tid >> 3) + 32 * j;
        asrc[j] = x + ((size_t)(b * T_ + mT * BM + row)) * D_ + ch * 4;
        bsrc[j] = W + (size_t)ids[row] * D_ + ch * 4;
    }

    f32x4 acc[4][4];
#pragma unroll
    for (int mi = 0; mi < 4; ++mi)
#pragma unroll
        for (int ni = 0; ni < 4; ++ni) acc[mi][ni] = (f32x4){0.f, 0.f, 0.f, 0.f};

    int w = tid >> 6, lane = tid & 63;
    int waveM = w >> 1, waveN = w & 1;
    int lr = lane & 15, lq = lane >> 4;

    for (int k0 = 0; k0 < D_; k0 += FBK) {
        __syncthreads();
#pragma unroll
        for (int j = 0; j < 4; ++j) {
            int row = (tid >> 3) + 32 * j;
            float4 va = *(const float4*)(asrc[j] + k0);
            s16x4 pa = {f2bf(va.x), f2bf(va.y), f2bf(va.z), f2bf(va.w)};
            *(s16x4*)&At[row * FBK + ch * 4] = pa;
            float4 vb = *(const float4*)(bsrc[j] + k0);
            s16x4 pb = {f2bf(vb.x), f2bf(vb.y), f2bf(vb.z), f2bf(vb.w)};
            *(s16x4*)&Bt[row * FBK + ch * 4] = pb;
        }
        __syncthreads();
        bf16x8 af[4], bfr[4];
#pragma unroll
        for (int mi = 0; mi < 4; ++mi)
            af[mi] = *(const bf16x8*)&At[(waveM * 64 + mi * 16 + lr) * FBK + lq * 8];
#pragma unroll
        for (int ni = 0; ni < 4; ++ni)
            bfr[ni] = *(const bf16x8*)&Bt[(waveN * 64 + ni * 16 + lr) * FBK + lq * 8];
#pragma unroll
        for (int mi = 0; mi < 4; ++mi)
#pragma unroll
            for (int ni = 0; ni < 4; ++ni)
                acc[mi][ni] = __builtin_amdgcn_mfma_f32_16x16x32_bf16(
                    af[mi], bfr[ni], acc[mi][ni], 0, 0, 0);
    }

    float* dptr = denom + b * T_ + mT * BM;
#pragma unroll
    for (int mi = 0; mi < 4; ++mi) {
#pragma unroll
        for (int rr = 0; rr < 4; ++rr) {
            int localRow = waveM * 64 + mi * 16 + lq * 4 + rr;
            int lab = labT[localRow];
            float sum = 0.0f;
#pragma unroll
            for (int ni = 0; ni < 4; ++ni) {
                int col = waveN * 64 + ni * 16 + lr;
                float v = acc[mi][ni][rr] + colbias[col];
                sum += (ids[col] == lab) ? 0.0f : __expf(v);
            }
            sum += __shfl_xor(sum, 1);
            sum += __shfl_xor(sum, 2);
            sum += __shfl_xor(sum, 4);
            sum += __shfl_xor(sum, 8);
            if (lr == 0) atomicAdd(&dptr[localRow], sum);
        }
    }
}

// ---------------------------------------------------------------------------
// Kernel 3: token_loss = log(denom) - true_logit; out = 0.5 * mean
__global__ __launch_bounds__(256) void finalize_kernel(
    const float* __restrict__ true_logit, const float* __restrict__ denom,
    float* __restrict__ out)
{
    float s = 0.0f;
    for (int i = threadIdx.x; i < B_ * T_; i += 256)
        s += __logf(denom[i]) - true_logit[i];
#pragma unroll
    for (int m = 32; m >= 1; m >>= 1) s += __shfl_xor(s, m);
    __shared__ float wsum[4];
    if ((threadIdx.x & 63) == 0) wsum[threadIdx.x >> 6] = s;
    __syncthreads();
    if (threadIdx.x == 0)
        out[0] = 0.5f * (wsum[0] + wsum[1] + wsum[2] + wsum[3]) / (float)(B_ * T_);
}

// ---------------------------------------------------------------------------
extern "C" void kernel_launch(void* const* d_in, const int* in_sizes, int n_in,
                              void* d_out, int out_size, void* d_ws, size_t ws_size,
                              hipStream_t stream) {
    const float* x       = (const float*)d_in[0];   // [B,T,D]
    const float* W       = (const float*)d_in[1];   // [N,D]
    const float* bvec    = (const float*)d_in[2];   // [N]
    const int*   labels  = (const int*)d_in[3];     // [B,T]
    const int*   sampled = (const int*)d_in[4];     // [B,S]
    float* out = (float*)d_out;

    float* true_logit   = (float*)d_ws;                 // B*T floats
    float* denom        = true_logit + B_ * T_;         // B*T floats
    unsigned char* xf8  = (unsigned char*)(denom + B_ * T_);  // B*T*D fp8 (16.8 MB)
    unsigned char* Wf8  = xf8 + (size_t)B_ * T_ * D_;   // N*D fp8 (51.2 MB)

    const size_t NEED = (size_t)2 * B_ * T_ * 4
                      + (size_t)B_ * T_ * D_
                      + (size_t)N_ * D_;               // ~68.2 MB

    if (ws_size >= NEED) {
        convert_w_kernel<<<N_ * D_ / 2048, 256, 0, stream>>>(W, Wf8);
        true_logit_kernel<true><<<B_ * T_ / 4, 256, 0, stream>>>(
            x, W, bvec, labels, true_logit, denom, xf8);
        sampled_gemm_fp8<<<B_ * (T_ / BM) * (S_ / BN), 256, 0, stream>>>(
            xf8, Wf8, bvec, labels, sampled, denom);
    } else {
        true_logit_kernel<false><<<B_ * T_ / 4, 256, 0, stream>>>(
            x, W, bvec, labels, true_logit, denom, nullptr);
        sampled_gemm<<<B_ * (T_ / BM) * (S_ / BN), 256, 0, stream>>>(
            x, W, bvec, labels, sampled, denom);
    }
    finalize_kernel<<<1, 256, 0, stream>>>(true_logit, denom, out);
}